// Round 2
// baseline (420.763 us; speedup 1.0000x reference)
//
#include <hip/hip_runtime.h>

#define B_ 1024
#define M_ 64
#define N_ 8192
#define NSG 16   // k-splits for k_G  (chunk 1024 of K=16384)
#define NS3 8    // n-slabs for k_H23 (1024 cols each)

typedef __attribute__((ext_vector_type(8))) short bf16x8;
typedef __attribute__((ext_vector_type(4))) float f32x4;

__device__ inline unsigned short f2b(float f) {
    union { float f; unsigned u; } v; v.f = f;
    unsigned r = v.u + 0x7FFFu + ((v.u >> 16) & 1u);
    return (unsigned short)(r >> 16);
}
__device__ inline unsigned rne2(float lo, float hi) {
    union { float f; unsigned u; } a, b; a.f = lo; b.f = hi;
    unsigned x = (a.u + 0x7FFFu + ((a.u >> 16) & 1u)) >> 16;
    unsigned y = (b.u + 0x7FFFu + ((b.u >> 16) & 1u)) >> 16;
    return x | (y << 16);
}
__device__ inline float b2f(unsigned short s) {
    union { unsigned u; float f; } v; v.u = ((unsigned)s) << 16; return v.f;
}
// readlane with uniform (dynamic) lane index -> SALU broadcast (r8-proven)
__device__ inline float rl(float v, int l) {
    return __builtin_bit_cast(float, __builtin_amdgcn_readlane(__builtin_bit_cast(int, v), l));
}

// ---------------------------------------------------------------------------
// generic fp32 -> bf16 stream (8 elems/thread)
__global__ __launch_bounds__(256) void k_cvt(const float* src, unsigned short* dst) {
    size_t i = ((size_t)blockIdx.x * 256 + threadIdx.x) * 8;
    float4 f0 = *(const float4*)(src + i);
    float4 f1 = *(const float4*)(src + i + 4);
    union { bf16x8 v; unsigned u[4]; } r;
    r.u[0] = rne2(f0.x, f0.y); r.u[1] = rne2(f0.z, f0.w);
    r.u[2] = rne2(f1.x, f1.y); r.u[3] = rne2(f1.z, f1.w);
    *(bf16x8*)(dst + i) = r.v;
}

// ---------------------------------------------------------------------------
// Fused A-prep: one pass over A produces Abf (bf16 copy), ATb (transpose,
// [n][c*64+m]), WgT ([o][k]: o<64 -> [Ar|-Ai], o>=64 -> [Ai|Ar]).
__global__ __launch_bounds__(256) void k_prep(const float* A, unsigned short* Abf,
                                              unsigned short* WgT, unsigned short* ATb) {
    __shared__ float tile[128][65];
    int n0 = blockIdx.x * 64;
    int t = threadIdx.x;
    int nl = t % 64, r0 = t / 64;
#pragma unroll
    for (int it = 0; it < 32; ++it) {
        int row = r0 + it * 4;                       // row = c*64+m
        tile[row][nl] = A[(size_t)row * N_ + n0 + nl];
    }
    __syncthreads();
    // Abf + WgT (row-major reads of tile)
#pragma unroll
    for (int it = 0; it < 32; ++it) {
        int row = r0 + it * 4;
        float v = tile[row][nl];
        unsigned short bv = f2b(v);
        Abf[(size_t)row * N_ + n0 + nl] = bv;
        if (row < 64) {   // Ar[m]
            WgT[(size_t)row * 16384 + n0 + nl] = bv;                 // o=m,    k-low
            WgT[(size_t)(64 + row) * 16384 + 8192 + n0 + nl] = bv;   // o=64+m, k-high
        } else {          // Ai[m], m=row-64
            int m = row - 64;
            WgT[(size_t)m * 16384 + 8192 + n0 + nl] = f2b(-v);       // o=m,    k-high
            WgT[(size_t)(64 + m) * 16384 + n0 + nl] = bv;            // o=64+m, k-low
        }
    }
    // ATb (transposed reads)
    int o = t % 128, nn0 = t / 128;
#pragma unroll
    for (int it = 0; it < 32; ++it) {
        int nn = nn0 + it * 2;
        ATb[(size_t)(n0 + nn) * 128 + o] = f2b(tile[o][nn]);
    }
}

// ---------------------------------------------------------------------------
// S = I/(rho+1e-12) + A A^H  (complex 64x64, Hermitian). fp32.
__global__ __launch_bounds__(256) void k_Sbuild(const float* A, const float* lr,
                                                float* S, float* AAHT) {
    __shared__ float redS[8];
    int bid = blockIdx.x;
    int i = 0, rem = bid;
    while (rem >= 64 - i) { rem -= 64 - i; ++i; }
    int j = i + rem;                       // i <= j
    int t = threadIdx.x;
    const float* Ar = A;
    const float* Ai = A + (size_t)M_ * N_;
    const float* ari = Ar + (size_t)i * N_;
    const float* aii = Ai + (size_t)i * N_;
    const float* arj = Ar + (size_t)j * N_;
    const float* aij = Ai + (size_t)j * N_;
    float aR = 0.f, aI = 0.f;
#pragma unroll
    for (int it = 0; it < 8; ++it) {
        int n = it * 1024 + t * 4;
        float4 xr = *(const float4*)(ari + n);
        float4 xi = *(const float4*)(aii + n);
        float4 br = *(const float4*)(arj + n);
        float4 bi = *(const float4*)(aij + n);
        aR += xr.x * br.x + xi.x * bi.x + xr.y * br.y + xi.y * bi.y
            + xr.z * br.z + xi.z * bi.z + xr.w * br.w + xi.w * bi.w;
        aI += xi.x * br.x - xr.x * bi.x + xi.y * br.y - xr.y * bi.y
            + xi.z * br.z - xr.z * bi.z + xi.w * br.w - xr.w * bi.w;
    }
    for (int off = 32; off > 0; off >>= 1) {
        aR += __shfl_down(aR, off, 64);
        aI += __shfl_down(aI, off, 64);
    }
    int lane = t & 63, w = t >> 6;
    if (lane == 0) { redS[w * 2] = aR; redS[w * 2 + 1] = aI; }
    __syncthreads();
    if (t == 0) {
        float R = redS[0] + redS[2] + redS[4] + redS[6];
        float I = redS[1] + redS[3] + redS[5] + redS[7];
        float inv_rho = 1.0f / (expf(lr[0]) + 1e-12f);
        float diag = (i == j) ? inv_rho : 0.f;
        S[((size_t)i * 64 + j) * 2 + 0] = R + diag;
        S[((size_t)i * 64 + j) * 2 + 1] = I;
        AAHT[((size_t)j * 64 + i) * 2 + 0] = R;
        AAHT[((size_t)j * 64 + i) * 2 + 1] = I;
        if (i != j) {
            S[((size_t)j * 64 + i) * 2 + 0] = R;
            S[((size_t)j * 64 + i) * 2 + 1] = -I;
            AAHT[((size_t)i * 64 + j) * 2 + 0] = R;
            AAHT[((size_t)i * 64 + j) * 2 + 1] = -I;
        }
    }
}

// ---------------------------------------------------------------------------
// k_Ginv: heterogeneous fused kernel.
//   block  0       : BLOCKED in-place complex Gauss-Jordan inverse of S -> Wt.
//                    Panel width 16; wave g owns columns 16g..16g+15.
//                    Per panel: owner wave does 16 register-only pivot steps
//                    (readlane, no LDS, no barriers), publishes the composed
//                    transform block Tp (= the in-place panel columns: each
//                    E_k = I - fp*e_k^T differs from I only in col k, so the
//                    product's panel block IS what in-place GJ leaves there);
//                    after ONE barrier, the other waves apply
//                      col <- mask_panelrows(col) + Tp * s_orig
//                    with s_orig = original panel-row values (closed form, no
//                    serial recurrence). Barriers: 64 -> 4. Critical path
//                    ~30k cyc (~12us), hidden under the concurrent GEMM.
//   blocks 1..1024 : Gpart[split][b][o] = sum_k rnb[b][k] * WgT[o][k] (MFMA)
// launch_bounds(256,2): VGPR cap 256; GJ trailing phase holds ~75 live VGPRs
// (32 state + 32 Tp row + temps) -> no spill.
__global__ __launch_bounds__(256, 2) void k_Ginv(const unsigned short* rnb,
                                                 const unsigned short* WgT,
                                                 float* Gpart,
                                                 const float* S, float* Wt) {
    int t = threadIdx.x;
    int lane = t & 63;
    if (blockIdx.x == 0) {
        // ---------------- blocked in-place inversion path ----------------
        __shared__ float2 Tp[2][16][64];   // [parity][panel col j][row]
        int g = t >> 6;                    // wave 0..3 owns cols 16g+J, J=0..15
        float mx0,my0,mx1,my1,mx2,my2,mx3,my3,mx4,my4,mx5,my5,mx6,my6,mx7,my7;
        float mx8,my8,mx9,my9,mx10,my10,mx11,my11,mx12,my12,mx13,my13,mx14,my14,mx15,my15;
#define GJ_INIT(J) { int c = 16 * g + (J);                                   \
    float2 v = ((const float2*)S)[(size_t)lane * 64 + c];                    \
    mx##J = v.x; my##J = v.y; }
        GJ_INIT(0) GJ_INIT(1) GJ_INIT(2) GJ_INIT(3) GJ_INIT(4) GJ_INIT(5) GJ_INIT(6) GJ_INIT(7)
        GJ_INIT(8) GJ_INIT(9) GJ_INIT(10) GJ_INIT(11) GJ_INIT(12) GJ_INIT(13) GJ_INIT(14) GJ_INIT(15)
#undef GJ_INIT

// one in-wave pivot step on own panel (k = 16p+j). Updates all 16 own cols.
#define FUP(J, j) if ((J) != (j)) {                                          \
    float sx = rl(mx##J, k), sy = rl(my##J, k);                              \
    float nx = a * mx##J - (fpx * sx - fpy * sy);                            \
    float ny = a * my##J - (fpx * sy + fpy * sx);                            \
    mx##J = nx; my##J = ny; }
#define FACT_STEP(j) {                                                       \
    int k = 16 * p + (j);                                                    \
    float px = rl(mx##j, k), py = rl(my##j, k);                              \
    float d = px * px + py * py;                                             \
    float id = 1.0f / d;                                                     \
    float pix = px * id, piy = -py * id;                                     \
    bool isk = (lane == k);                                                  \
    float a   = isk ? 0.f : 1.f;                                             \
    float fpx = isk ? -pix : (mx##j * pix - my##j * piy);                    \
    float fpy = isk ? -piy : (mx##j * piy + my##j * pix);                    \
    FUP(0, j) FUP(1, j) FUP(2, j) FUP(3, j) FUP(4, j) FUP(5, j) FUP(6, j) FUP(7, j) \
    FUP(8, j) FUP(9, j) FUP(10, j) FUP(11, j) FUP(12, j) FUP(13, j) FUP(14, j) FUP(15, j) \
    mx##j = -fpx; my##j = -fpy; }

        for (int p = 0; p < 4; ++p) {
            const int buf = p & 1;
            if (g == p) {
                // panel factorization: 16 serial in-register pivot steps
                FACT_STEP(0)  FACT_STEP(1)  FACT_STEP(2)  FACT_STEP(3)
                FACT_STEP(4)  FACT_STEP(5)  FACT_STEP(6)  FACT_STEP(7)
                FACT_STEP(8)  FACT_STEP(9)  FACT_STEP(10) FACT_STEP(11)
                FACT_STEP(12) FACT_STEP(13) FACT_STEP(14) FACT_STEP(15)
                // publish composed transform block Tp
#define GJ_PUB(J) Tp[buf][J][lane] = make_float2(mx##J, my##J);
                GJ_PUB(0) GJ_PUB(1) GJ_PUB(2) GJ_PUB(3) GJ_PUB(4) GJ_PUB(5) GJ_PUB(6) GJ_PUB(7)
                GJ_PUB(8) GJ_PUB(9) GJ_PUB(10) GJ_PUB(11) GJ_PUB(12) GJ_PUB(13) GJ_PUB(14) GJ_PUB(15)
#undef GJ_PUB
            }
            __syncthreads();
            if (g != p) {
                // load Tp row for this lane (conflict-free: per j, lanes read
                // consecutive float2)
#define TL(j) float tx##j = Tp[buf][j][lane].x, ty##j = Tp[buf][j][lane].y;
                TL(0) TL(1) TL(2) TL(3) TL(4) TL(5) TL(6) TL(7)
                TL(8) TL(9) TL(10) TL(11) TL(12) TL(13) TL(14) TL(15)
#undef TL
                float msk = ((lane >> 4) == p) ? 0.f : 1.f;
// col <- msk*col + sum_j Tp[:,j] * s_orig_j ; all rl's of mx##J precede its write
#define TFMA(j, J) { float sx = rl(mx##J, 16 * p + (j)), sy = rl(my##J, 16 * p + (j)); \
    ax += tx##j * sx - ty##j * sy; ay += tx##j * sy + ty##j * sx; }
#define TRAIL_COL(J) { float ax = msk * mx##J, ay = msk * my##J;             \
    TFMA(0, J) TFMA(1, J) TFMA(2, J) TFMA(3, J) TFMA(4, J) TFMA(5, J) TFMA(6, J) TFMA(7, J) \
    TFMA(8, J) TFMA(9, J) TFMA(10, J) TFMA(11, J) TFMA(12, J) TFMA(13, J) TFMA(14, J) TFMA(15, J) \
    mx##J = ax; my##J = ay; }
                TRAIL_COL(0)  TRAIL_COL(1)  TRAIL_COL(2)  TRAIL_COL(3)
                TRAIL_COL(4)  TRAIL_COL(5)  TRAIL_COL(6)  TRAIL_COL(7)
                TRAIL_COL(8)  TRAIL_COL(9)  TRAIL_COL(10) TRAIL_COL(11)
                TRAIL_COL(12) TRAIL_COL(13) TRAIL_COL(14) TRAIL_COL(15)
#undef TRAIL_COL
#undef TFMA
            }
        }
#undef FACT_STEP
#undef FUP
#define GJ_OUT(J) { int c = 16 * g + (J);                                    \
    ((float2*)Wt)[(size_t)c * 64 + lane] = make_float2(mx##J, my##J); }
        GJ_OUT(0) GJ_OUT(1) GJ_OUT(2) GJ_OUT(3) GJ_OUT(4) GJ_OUT(5) GJ_OUT(6) GJ_OUT(7)
        GJ_OUT(8) GJ_OUT(9) GJ_OUT(10) GJ_OUT(11) GJ_OUT(12) GJ_OUT(13) GJ_OUT(14) GJ_OUT(15)
#undef GJ_OUT
        return;
    }
    // ---------------- GEMM path (k_G) ----------------
    int bx = blockIdx.x - 1;
    int w = t >> 6;
    int l15 = lane & 15;
    int q8 = (lane >> 4) * 8;
    int split = bx & 15;
    int b0 = (bx >> 4) * 16;
    int k0 = split * 1024;
    f32x4 a00 = {}, a01 = {};
    const unsigned short* x0 = rnb + (size_t)(b0 + l15) * 16384 + k0 + q8;
    const unsigned short* w0 = WgT + (size_t)(w * 32 + l15) * 16384 + k0 + q8;
    const unsigned short* w1 = w0 + (size_t)16 * 16384;
#pragma unroll 8
    for (int ks = 0; ks < 32; ++ks) {
        int kk = ks * 32;
        bf16x8 af0 = *(const bf16x8*)(x0 + kk);
        bf16x8 bf0 = *(const bf16x8*)(w0 + kk);
        bf16x8 bf1 = *(const bf16x8*)(w1 + kk);
        a00 = __builtin_amdgcn_mfma_f32_16x16x32_bf16(af0, bf0, a00, 0, 0, 0);
        a01 = __builtin_amdgcn_mfma_f32_16x16x32_bf16(af0, bf1, a01, 0, 0, 0);
    }
    int row = (lane >> 4) * 4;
    size_t base = (size_t)split * (B_ * 128);
    float* g = Gpart + base + (size_t)(b0 + row) * 128 + w * 32 + l15;
#pragma unroll
    for (int r = 0; r < 4; ++r) {
        g[(size_t)r * 128] = a00[r];
        g[(size_t)r * 128 + 16] = a01[r];
    }
}

// ---------------------------------------------------------------------------
// per-step small: Ab = sum(Gpart) + rho*AAH*(z-u);  qb = bf16(rho*(z-u) - S^-1*Ab)
__global__ __launch_bounds__(256) void k_small12(const float* Gpart, const float* AAHT,
                                                 const float* Wt, const float* zin,
                                                 const float* uin, const float* lr,
                                                 unsigned short* qb) {
    __shared__ float2 AbS[4][64];
    int t = threadIdx.x;
    int m = t & 63;
    int w = __builtin_amdgcn_readfirstlane(t >> 6);
    int b = blockIdx.x * 4 + w;
    float rho = expf(lr[0]);
    float abR = 0.f, abI = 0.f;
    for (int k = 0; k < 64; ++k) {
        float wr = zin[(b * 2 + 0) * 64 + k] - uin[(b * 2 + 0) * 64 + k];
        float wi = zin[(b * 2 + 1) * 64 + k] - uin[(b * 2 + 1) * 64 + k];
        float2 h = *(const float2*)(AAHT + ((size_t)k * 64 + m) * 2);  // AAH[m][k]
        abR += wr * h.x - wi * h.y;
        abI += wi * h.x + wr * h.y;
    }
    float gR = 0.f, gI = 0.f;
#pragma unroll
    for (int s = 0; s < NSG; ++s) {
        gR += Gpart[(size_t)s * 131072 + (size_t)b * 128 + m];
        gI += Gpart[(size_t)s * 131072 + (size_t)b * 128 + 64 + m];
    }
    abR = gR + rho * abR;
    abI = gI + rho * abI;
    AbS[w][m] = make_float2(abR, abI);
    __syncthreads();
    float tR = 0.f, tI = 0.f;
    for (int k = 0; k < 64; ++k) {
        float2 Wv = *(const float2*)(Wt + ((size_t)k * 64 + m) * 2);   // W[m][k]
        float2 ab = AbS[w][k];
        tR += ab.x * Wv.x - ab.y * Wv.y;
        tI += ab.y * Wv.x + ab.x * Wv.y;
    }
    float wr_m = zin[(b * 2 + 0) * 64 + m] - uin[(b * 2 + 0) * 64 + m];
    float wi_m = zin[(b * 2 + 1) * 64 + m] - uin[(b * 2 + 1) * 64 + m];
    qb[(size_t)b * 128 + m] = f2b(rho * wr_m - tR);
    qb[(size_t)b * 128 + 64 + m] = f2b(rho * wi_m - tI);
}

// ---------------------------------------------------------------------------
// k_H23: fused x-update + Ax partials; last step also writes fp32 out (real)
// and zeros the imag rows (absorbs k_zero_imag). rn read as bf16 (rnb).
__global__ __launch_bounds__(256, 3) void k_H23(const unsigned short* qb, const unsigned short* ATb,
                                                const unsigned short* rnb, const unsigned short* Abf,
                                                float* out, float* Axpart, int last) {
    __shared__ __align__(16) char lds_buf[4 * 8448];
    int t = threadIdx.x;
    int lane = t & 63;
    int w = t >> 6;
    int l15 = lane & 15;
    int q8 = (lane >> 4) * 8;
    int row = (lane >> 4) * 4;
    int slab = blockIdx.x;
    int b0 = blockIdx.y * 16;
    int n0 = slab * 1024 + w * 256;
    short* xs = (short*)(lds_buf + w * 8448);      // [16][264] bf16 (row stride 528B)
    float* rs = (float*)(lds_buf + w * 8448);      // [16][132] fp32 alias (same wave only)

    // ---- phase 1
    bf16x8 a[4];
    const unsigned short* qrow = qb + (size_t)(b0 + l15) * 128 + q8;
#pragma unroll
    for (int ks = 0; ks < 4; ++ks) a[ks] = *(const bf16x8*)(qrow + ks * 32);
#pragma unroll 2
    for (int nt = 0; nt < 16; ++nt) {
        f32x4 acc = {};
        const unsigned short* bbase = ATb + (size_t)(n0 + nt * 16 + l15) * 128 + q8;
#pragma unroll
        for (int ks = 0; ks < 4; ++ks) {
            bf16x8 bf = *(const bf16x8*)(bbase + ks * 32);
            acc = __builtin_amdgcn_mfma_f32_16x16x32_bf16(a[ks], bf, acc, 0, 0, 0);
        }
        int ncol = n0 + nt * 16 + l15;
        int nloc = nt * 16 + l15;
#pragma unroll
        for (int r = 0; r < 4; ++r) {
            size_t ridx = (size_t)(b0 + row + r) * 16384 + ncol;   // real row of rn/out
            float v = fmaxf(acc[r] + b2f(rnb[ridx]), 0.f);
            if (last) out[ridx] = v;
            xs[(row + r) * 264 + nloc] = (short)f2b(v);
        }
    }
    // ---- phase 2 (wave-private x-stage: lgkmcnt orders RAW)
    f32x4 acc8[8] = {};
#pragma unroll
    for (int ks = 0; ks < 8; ++ks) {
        bf16x8 xf = *(const bf16x8*)(xs + l15 * 264 + ks * 32 + q8);
#pragma unroll
        for (int ot = 0; ot < 8; ++ot) {
            const unsigned short* bp = Abf + (size_t)(ot * 16 + l15) * 8192 + n0 + ks * 32 + q8;
            acc8[ot] = __builtin_amdgcn_mfma_f32_16x16x32_bf16(xf, *(const bf16x8*)bp, acc8[ot], 0, 0, 0);
        }
    }
    // ---- phase 3
    __syncthreads();
#pragma unroll
    for (int ot = 0; ot < 8; ++ot)
#pragma unroll
        for (int r = 0; r < 4; ++r)
            rs[(row + r) * 132 + ot * 16 + l15] = acc8[ot][r];
    __syncthreads();
#pragma unroll
    for (int e = t; e < 2048; e += 256) {
        int b = e >> 7, o = e & 127;
        float sAx = 0.f;
#pragma unroll
        for (int ww = 0; ww < 4; ++ww)
            sAx += ((const float*)(lds_buf + ww * 8448))[b * 132 + o];
        Axpart[(size_t)slab * 131072 + (size_t)(b0 + b) * 128 + o] = sAx;
    }
    // ---- zero imag rows of out (absorbed k_zero_imag)
    if (last) {
        float4 z4 = make_float4(0.f, 0.f, 0.f, 0.f);
        for (int e = t; e < 4096; e += 256) {
            int bb = e >> 8, nq = e & 255;
            *(float4*)(out + ((size_t)(b0 + bb) * 2 + 1) * N_ + slab * 1024 + nq * 4) = z4;
        }
    }
}

// ---------------------------------------------------------------------------
// per-step epilogue
__global__ __launch_bounds__(128) void k_small3(const float* Axpart, const float* uin,
                                                const float* y, const float* le,
                                                float* z, float* u, float* uout, int last) {
    __shared__ float red[2];
    int b = blockIdx.x, t = threadIdx.x;
    size_t idx = (size_t)b * 128 + t;
    float ax = 0.f;
#pragma unroll
    for (int s = 0; s < NS3; ++s) ax += Axpart[(size_t)s * 131072 + idx];
    float uo = uin[idx], yv = y[idx];
    float v = ax + uo - yv;
    float sq = v * v;
    for (int off = 32; off > 0; off >>= 1) sq += __shfl_down(sq, off, 64);
    if ((t & 63) == 0) red[t >> 6] = sq;
    __syncthreads();
    float tot = red[0] + red[1];
    float eps = expf(le[0]);
    float scale = fminf(1.f, eps / (sqrtf(tot) + 1e-12f));
    float zv = yv + v * scale;
    float un = uo + ax - zv;
    z[idx] = zv;
    u[idx] = un;
    if (last) uout[idx] = un;
}

// ---------------------------------------------------------------------------
extern "C" void kernel_launch(void* const* d_in, const int* in_sizes, int n_in,
                              void* d_out, int out_size, void* d_ws, size_t ws_size,
                              hipStream_t stream) {
    const float* rn  = (const float*)d_in[0];   // (B,2,N)
    const float* y   = (const float*)d_in[1];   // (B,2,M)
    const float* uin = (const float*)d_in[2];   // (B,2,M)
    const float* A   = (const float*)d_in[3];   // (2,M,N)
    const float* lr  = (const float*)d_in[4];   // log_rho
    const float* le  = (const float*)d_in[5];   // log_epsilon

    float* out = (float*)d_out;
    float* ws  = (float*)d_ws;

    float* Gpart  = ws;                             // 16*131072 = 2,097,152 f
    float* Axpart = Gpart + (size_t)NSG * 131072;   //  8*131072 = 1,048,576 f
    float* S      = Axpart + (size_t)NS3 * 131072;  // 8192
    float* AAHT   = S + 8192;                       // 8192
    float* Wt     = AAHT + 8192;                    // 8192
    float* z      = Wt + 8192;                      // 131072
    float* u      = z + 131072;                     // 131072
    unsigned short* qb  = (unsigned short*)(u + 131072);  // 131,072 us
    unsigned short* rnb = qb + 131072;              // B*2*N  = 16,777,216 us
    unsigned short* WgT = rnb + (size_t)B_ * 16384; // 128*16384 = 2,097,152 us
    unsigned short* Abf = WgT + 2097152;            // 2*64*8192 = 1,048,576 us
    unsigned short* ATb = Abf + 1048576;            // 8192*128  = 1,048,576 us
    float* uout = out + (size_t)B_ * 2 * N_;

    k_prep<<<128, 256, 0, stream>>>(A, Abf, WgT, ATb);
    k_cvt<<<8192, 256, 0, stream>>>(rn, rnb);
    k_Sbuild<<<2080, 256, 0, stream>>>(A, lr, S, AAHT);
    k_Ginv<<<1025, 256, 0, stream>>>(rnb, WgT, Gpart, S, Wt);

    for (int step = 0; step < 3; ++step) {
        const float* zp = (step == 0) ? y   : z;
        const float* up = (step == 0) ? uin : u;
        int last = (step == 2) ? 1 : 0;
        k_small12<<<256, 256, 0, stream>>>(Gpart, AAHT, Wt, zp, up, lr, qb);
        k_H23<<<dim3(NS3, 64), 256, 0, stream>>>(qb, ATb, rnb, Abf, out, Axpart, last);
        k_small3<<<B_, 128, 0, stream>>>(Axpart, up, y, le, z, u, uout, last);
    }
}

// Round 3
// 369.694 us; speedup vs baseline: 1.1381x; 1.1381x over previous
//
#include <hip/hip_runtime.h>

#define B_ 1024
#define M_ 64
#define N_ 8192
#define NSG 16   // k-splits for k_G  (chunk 1024 of K=16384)
#define NS3 8    // n-slabs for k_H23 (1024 cols each)

typedef __attribute__((ext_vector_type(8))) short bf16x8;
typedef __attribute__((ext_vector_type(4))) float f32x4;

__device__ inline unsigned short f2b(float f) {
    union { float f; unsigned u; } v; v.f = f;
    unsigned r = v.u + 0x7FFFu + ((v.u >> 16) & 1u);
    return (unsigned short)(r >> 16);
}
__device__ inline unsigned rne2(float lo, float hi) {
    union { float f; unsigned u; } a, b; a.f = lo; b.f = hi;
    unsigned x = (a.u + 0x7FFFu + ((a.u >> 16) & 1u)) >> 16;
    unsigned y = (b.u + 0x7FFFu + ((b.u >> 16) & 1u)) >> 16;
    return x | (y << 16);
}
__device__ inline float b2f(unsigned short s) {
    union { unsigned u; float f; } v; v.u = ((unsigned)s) << 16; return v.f;
}
// readlane with uniform (dynamic) lane index -> SALU broadcast (r8-proven)
__device__ inline float rl(float v, int l) {
    return __builtin_bit_cast(float, __builtin_amdgcn_readlane(__builtin_bit_cast(int, v), l));
}

// ---------------------------------------------------------------------------
// generic fp32 -> bf16 stream (8 elems/thread)
__global__ __launch_bounds__(256) void k_cvt(const float* src, unsigned short* dst) {
    size_t i = ((size_t)blockIdx.x * 256 + threadIdx.x) * 8;
    float4 f0 = *(const float4*)(src + i);
    float4 f1 = *(const float4*)(src + i + 4);
    union { bf16x8 v; unsigned u[4]; } r;
    r.u[0] = rne2(f0.x, f0.y); r.u[1] = rne2(f0.z, f0.w);
    r.u[2] = rne2(f1.x, f1.y); r.u[3] = rne2(f1.z, f1.w);
    *(bf16x8*)(dst + i) = r.v;
}

// ---------------------------------------------------------------------------
// Fused A-prep: one pass over A produces Abf (bf16 copy), ATb (transpose,
// [n][c*64+m]), WgT ([o][k]: o<64 -> [Ar|-Ai], o>=64 -> [Ai|Ar]).
__global__ __launch_bounds__(256) void k_prep(const float* A, unsigned short* Abf,
                                              unsigned short* WgT, unsigned short* ATb) {
    __shared__ float tile[128][65];
    int n0 = blockIdx.x * 64;
    int t = threadIdx.x;
    int nl = t % 64, r0 = t / 64;
#pragma unroll
    for (int it = 0; it < 32; ++it) {
        int row = r0 + it * 4;                       // row = c*64+m
        tile[row][nl] = A[(size_t)row * N_ + n0 + nl];
    }
    __syncthreads();
    // Abf + WgT (row-major reads of tile)
#pragma unroll
    for (int it = 0; it < 32; ++it) {
        int row = r0 + it * 4;
        float v = tile[row][nl];
        unsigned short bv = f2b(v);
        Abf[(size_t)row * N_ + n0 + nl] = bv;
        if (row < 64) {   // Ar[m]
            WgT[(size_t)row * 16384 + n0 + nl] = bv;                 // o=m,    k-low
            WgT[(size_t)(64 + row) * 16384 + 8192 + n0 + nl] = bv;   // o=64+m, k-high
        } else {          // Ai[m], m=row-64
            int m = row - 64;
            WgT[(size_t)m * 16384 + 8192 + n0 + nl] = f2b(-v);       // o=m,    k-high
            WgT[(size_t)(64 + m) * 16384 + n0 + nl] = bv;            // o=64+m, k-low
        }
    }
    // ATb (transposed reads)
    int o = t % 128, nn0 = t / 128;
#pragma unroll
    for (int it = 0; it < 32; ++it) {
        int nn = nn0 + it * 2;
        ATb[(size_t)(n0 + nn) * 128 + o] = f2b(tile[o][nn]);
    }
}

// ---------------------------------------------------------------------------
// S = I/(rho+1e-12) + A A^H  (complex 64x64, Hermitian). fp32.
__global__ __launch_bounds__(256) void k_Sbuild(const float* A, const float* lr,
                                                float* S, float* AAHT) {
    __shared__ float redS[8];
    int bid = blockIdx.x;
    int i = 0, rem = bid;
    while (rem >= 64 - i) { rem -= 64 - i; ++i; }
    int j = i + rem;                       // i <= j
    int t = threadIdx.x;
    const float* Ar = A;
    const float* Ai = A + (size_t)M_ * N_;
    const float* ari = Ar + (size_t)i * N_;
    const float* aii = Ai + (size_t)i * N_;
    const float* arj = Ar + (size_t)j * N_;
    const float* aij = Ai + (size_t)j * N_;
    float aR = 0.f, aI = 0.f;
#pragma unroll
    for (int it = 0; it < 8; ++it) {
        int n = it * 1024 + t * 4;
        float4 xr = *(const float4*)(ari + n);
        float4 xi = *(const float4*)(aii + n);
        float4 br = *(const float4*)(arj + n);
        float4 bi = *(const float4*)(aij + n);
        aR += xr.x * br.x + xi.x * bi.x + xr.y * br.y + xi.y * bi.y
            + xr.z * br.z + xi.z * bi.z + xr.w * br.w + xi.w * bi.w;
        aI += xi.x * br.x - xr.x * bi.x + xi.y * br.y - xr.y * bi.y
            + xi.z * br.z - xr.z * bi.z + xi.w * br.w - xr.w * bi.w;
    }
    for (int off = 32; off > 0; off >>= 1) {
        aR += __shfl_down(aR, off, 64);
        aI += __shfl_down(aI, off, 64);
    }
    int lane = t & 63, w = t >> 6;
    if (lane == 0) { redS[w * 2] = aR; redS[w * 2 + 1] = aI; }
    __syncthreads();
    if (t == 0) {
        float R = redS[0] + redS[2] + redS[4] + redS[6];
        float I = redS[1] + redS[3] + redS[5] + redS[7];
        float inv_rho = 1.0f / (expf(lr[0]) + 1e-12f);
        float diag = (i == j) ? inv_rho : 0.f;
        S[((size_t)i * 64 + j) * 2 + 0] = R + diag;
        S[((size_t)i * 64 + j) * 2 + 1] = I;
        AAHT[((size_t)j * 64 + i) * 2 + 0] = R;
        AAHT[((size_t)j * 64 + i) * 2 + 1] = I;
        if (i != j) {
            S[((size_t)j * 64 + i) * 2 + 0] = R;
            S[((size_t)j * 64 + i) * 2 + 1] = -I;
            AAHT[((size_t)i * 64 + j) * 2 + 0] = R;
            AAHT[((size_t)i * 64 + j) * 2 + 1] = -I;
        }
    }
}

// ---------------------------------------------------------------------------
// k_Ginv: heterogeneous fused kernel.
//   block  0       : IN-PLACE complex Gauss-Jordan inverse of S -> Wt (round-1
//                    proven structure: 4 waves x 16 interleaved cols c=4J+g,
//                    32 named floats/thread, 48-VGPR envelope, 1KB LDS).
//                    NEW: the whole GJ path runs at s_setprio(1). Round-1
//                    showed k_Ginv = GEMM(31us) + GJ(44us) ADDITIVE: the GJ
//                    waves got ~1/8 of issue slots while 8 waves/SIMD of GEMM
//                    were resident, so the inversion made almost no progress
//                    until the GEMM drained. Priority 1 wins arbitration ->
//                    GJ proceeds at ~solo rate under the GEMM (costs issue
//                    slots on 1 CU of 256).
//   blocks 1..1024 : Gpart[split][b][o] = sum_k rnb[b][k] * WgT[o][k] (MFMA)
// launch_bounds(256,2): VGPR cap 256; both paths fit 48 VGPR -> 8 blocks/CU
// capacity, so block 0 is co-resident from t=0 (r2 lesson: resource bloat
// that drops capacity to exactly the GEMM's 4 blocks/CU delays the GJ start).
__global__ __launch_bounds__(256, 2) void k_Ginv(const unsigned short* rnb,
                                                 const unsigned short* WgT,
                                                 float* Gpart,
                                                 const float* S, float* Wt) {
    int t = threadIdx.x;
    int lane = t & 63;
    if (blockIdx.x == 0) {
        // ---------------- in-place inversion path ----------------
        __builtin_amdgcn_s_setprio(1);
        // state: m[J] = M[lane][4J+g], J=0..15.  M starts as S, ends as S^-1.
        __shared__ float2 fvs[2][64];
        int g = t >> 6;             // wave 0..3: owns columns 4J+g, J=0..15
        float mx0,my0,mx1,my1,mx2,my2,mx3,my3,mx4,my4,mx5,my5,mx6,my6,mx7,my7;
        float mx8,my8,mx9,my9,mx10,my10,mx11,my11,mx12,my12,mx13,my13,mx14,my14,mx15,my15;
#define GJ_INIT(J) { int c = 4 * (J) + g;                                    \
    float2 v = ((const float2*)S)[(size_t)lane * 64 + c];                    \
    mx##J = v.x; my##J = v.y; }
        GJ_INIT(0) GJ_INIT(1) GJ_INIT(2) GJ_INIT(3) GJ_INIT(4) GJ_INIT(5) GJ_INIT(6) GJ_INIT(7)
        GJ_INIT(8) GJ_INIT(9) GJ_INIT(10) GJ_INIT(11) GJ_INIT(12) GJ_INIT(13) GJ_INIT(14) GJ_INIT(15)
#undef GJ_INIT
        for (int k = 0; k < 64; ++k) {
            const int par = k & 1;
            if (g == (k & 3)) {              // publish column k (pre-update)
                switch (k >> 2) {
                    case 0:  fvs[par][lane] = make_float2(mx0,  my0);  break;
                    case 1:  fvs[par][lane] = make_float2(mx1,  my1);  break;
                    case 2:  fvs[par][lane] = make_float2(mx2,  my2);  break;
                    case 3:  fvs[par][lane] = make_float2(mx3,  my3);  break;
                    case 4:  fvs[par][lane] = make_float2(mx4,  my4);  break;
                    case 5:  fvs[par][lane] = make_float2(mx5,  my5);  break;
                    case 6:  fvs[par][lane] = make_float2(mx6,  my6);  break;
                    case 7:  fvs[par][lane] = make_float2(mx7,  my7);  break;
                    case 8:  fvs[par][lane] = make_float2(mx8,  my8);  break;
                    case 9:  fvs[par][lane] = make_float2(mx9,  my9);  break;
                    case 10: fvs[par][lane] = make_float2(mx10, my10); break;
                    case 11: fvs[par][lane] = make_float2(mx11, my11); break;
                    case 12: fvs[par][lane] = make_float2(mx12, my12); break;
                    case 13: fvs[par][lane] = make_float2(mx13, my13); break;
                    case 14: fvs[par][lane] = make_float2(mx14, my14); break;
                    default: fvs[par][lane] = make_float2(mx15, my15); break;
                }
            }
            __syncthreads();
            float2 f = fvs[par][lane];          // M[lane][k] (pre-update col k)
            float2 p = fvs[par][k];             // M[k][k]
            float d = p.x * p.x + p.y * p.y;
            float id = 1.0f / d;
            float pix = p.x * id, piy = -p.y * id;          // 1/pivot
            bool isk = (lane == k);
            float a   = isk ? 0.f : 1.f;
            float fpx = isk ? -pix : (f.x * pix - f.y * piy);
            float fpy = isk ? -piy : (f.x * piy + f.y * pix);
            // column c != k:  M[i][c] = a*M[i][c] - fp*M[k][c]   (in-place GJ)
            // column c == k:  M[i][k] = -fp   (= -M[i][k]/p, diag -> 1/p)
#define GJ_UP(J) { if (4 * (J) + g == k) { mx##J = -fpx; my##J = -fpy; }     \
    else {                                                                   \
    float sx = rl(mx##J, k), sy = rl(my##J, k);                              \
    float nx = a * mx##J - (fpx * sx - fpy * sy);                            \
    float ny = a * my##J - (fpx * sy + fpy * sx);                            \
    mx##J = nx; my##J = ny; } }
            GJ_UP(0) GJ_UP(1) GJ_UP(2) GJ_UP(3) GJ_UP(4) GJ_UP(5) GJ_UP(6) GJ_UP(7)
            GJ_UP(8) GJ_UP(9) GJ_UP(10) GJ_UP(11) GJ_UP(12) GJ_UP(13) GJ_UP(14) GJ_UP(15)
#undef GJ_UP
        }
#define GJ_OUT(J) { int c = 4 * (J) + g;                                     \
    ((float2*)Wt)[(size_t)c * 64 + lane] = make_float2(mx##J, my##J); }
        GJ_OUT(0) GJ_OUT(1) GJ_OUT(2) GJ_OUT(3) GJ_OUT(4) GJ_OUT(5) GJ_OUT(6) GJ_OUT(7)
        GJ_OUT(8) GJ_OUT(9) GJ_OUT(10) GJ_OUT(11) GJ_OUT(12) GJ_OUT(13) GJ_OUT(14) GJ_OUT(15)
#undef GJ_OUT
        __builtin_amdgcn_s_setprio(0);
        return;
    }
    // ---------------- GEMM path (k_G) ----------------
    int bx = blockIdx.x - 1;
    int w = t >> 6;
    int l15 = lane & 15;
    int q8 = (lane >> 4) * 8;
    int split = bx & 15;
    int b0 = (bx >> 4) * 16;
    int k0 = split * 1024;
    f32x4 a00 = {}, a01 = {};
    const unsigned short* x0 = rnb + (size_t)(b0 + l15) * 16384 + k0 + q8;
    const unsigned short* w0 = WgT + (size_t)(w * 32 + l15) * 16384 + k0 + q8;
    const unsigned short* w1 = w0 + (size_t)16 * 16384;
#pragma unroll 8
    for (int ks = 0; ks < 32; ++ks) {
        int kk = ks * 32;
        bf16x8 af0 = *(const bf16x8*)(x0 + kk);
        bf16x8 bf0 = *(const bf16x8*)(w0 + kk);
        bf16x8 bf1 = *(const bf16x8*)(w1 + kk);
        a00 = __builtin_amdgcn_mfma_f32_16x16x32_bf16(af0, bf0, a00, 0, 0, 0);
        a01 = __builtin_amdgcn_mfma_f32_16x16x32_bf16(af0, bf1, a01, 0, 0, 0);
    }
    int row = (lane >> 4) * 4;
    size_t base = (size_t)split * (B_ * 128);
    float* g = Gpart + base + (size_t)(b0 + row) * 128 + w * 32 + l15;
#pragma unroll
    for (int r = 0; r < 4; ++r) {
        g[(size_t)r * 128] = a00[r];
        g[(size_t)r * 128 + 16] = a01[r];
    }
}

// ---------------------------------------------------------------------------
// per-step small: Ab = sum(Gpart) + rho*AAH*(z-u);  qb = bf16(rho*(z-u) - S^-1*Ab)
__global__ __launch_bounds__(256) void k_small12(const float* Gpart, const float* AAHT,
                                                 const float* Wt, const float* zin,
                                                 const float* uin, const float* lr,
                                                 unsigned short* qb) {
    __shared__ float2 AbS[4][64];
    int t = threadIdx.x;
    int m = t & 63;
    int w = __builtin_amdgcn_readfirstlane(t >> 6);
    int b = blockIdx.x * 4 + w;
    float rho = expf(lr[0]);
    float abR = 0.f, abI = 0.f;
    for (int k = 0; k < 64; ++k) {
        float wr = zin[(b * 2 + 0) * 64 + k] - uin[(b * 2 + 0) * 64 + k];
        float wi = zin[(b * 2 + 1) * 64 + k] - uin[(b * 2 + 1) * 64 + k];
        float2 h = *(const float2*)(AAHT + ((size_t)k * 64 + m) * 2);  // AAH[m][k]
        abR += wr * h.x - wi * h.y;
        abI += wi * h.x + wr * h.y;
    }
    float gR = 0.f, gI = 0.f;
#pragma unroll
    for (int s = 0; s < NSG; ++s) {
        gR += Gpart[(size_t)s * 131072 + (size_t)b * 128 + m];
        gI += Gpart[(size_t)s * 131072 + (size_t)b * 128 + 64 + m];
    }
    abR = gR + rho * abR;
    abI = gI + rho * abI;
    AbS[w][m] = make_float2(abR, abI);
    __syncthreads();
    float tR = 0.f, tI = 0.f;
    for (int k = 0; k < 64; ++k) {
        float2 Wv = *(const float2*)(Wt + ((size_t)k * 64 + m) * 2);   // W[m][k]
        float2 ab = AbS[w][k];
        tR += ab.x * Wv.x - ab.y * Wv.y;
        tI += ab.y * Wv.x + ab.x * Wv.y;
    }
    float wr_m = zin[(b * 2 + 0) * 64 + m] - uin[(b * 2 + 0) * 64 + m];
    float wi_m = zin[(b * 2 + 1) * 64 + m] - uin[(b * 2 + 1) * 64 + m];
    qb[(size_t)b * 128 + m] = f2b(rho * wr_m - tR);
    qb[(size_t)b * 128 + 64 + m] = f2b(rho * wi_m - tI);
}

// ---------------------------------------------------------------------------
// k_H23: fused x-update + Ax partials; last step also writes fp32 out (real)
// and zeros the imag rows (absorbs k_zero_imag). rn read as bf16 (rnb).
__global__ __launch_bounds__(256, 3) void k_H23(const unsigned short* qb, const unsigned short* ATb,
                                                const unsigned short* rnb, const unsigned short* Abf,
                                                float* out, float* Axpart, int last) {
    __shared__ __align__(16) char lds_buf[4 * 8448];
    int t = threadIdx.x;
    int lane = t & 63;
    int w = t >> 6;
    int l15 = lane & 15;
    int q8 = (lane >> 4) * 8;
    int row = (lane >> 4) * 4;
    int slab = blockIdx.x;
    int b0 = blockIdx.y * 16;
    int n0 = slab * 1024 + w * 256;
    short* xs = (short*)(lds_buf + w * 8448);      // [16][264] bf16 (row stride 528B)
    float* rs = (float*)(lds_buf + w * 8448);      // [16][132] fp32 alias (same wave only)

    // ---- phase 1
    bf16x8 a[4];
    const unsigned short* qrow = qb + (size_t)(b0 + l15) * 128 + q8;
#pragma unroll
    for (int ks = 0; ks < 4; ++ks) a[ks] = *(const bf16x8*)(qrow + ks * 32);
#pragma unroll 2
    for (int nt = 0; nt < 16; ++nt) {
        f32x4 acc = {};
        const unsigned short* bbase = ATb + (size_t)(n0 + nt * 16 + l15) * 128 + q8;
#pragma unroll
        for (int ks = 0; ks < 4; ++ks) {
            bf16x8 bf = *(const bf16x8*)(bbase + ks * 32);
            acc = __builtin_amdgcn_mfma_f32_16x16x32_bf16(a[ks], bf, acc, 0, 0, 0);
        }
        int ncol = n0 + nt * 16 + l15;
        int nloc = nt * 16 + l15;
#pragma unroll
        for (int r = 0; r < 4; ++r) {
            size_t ridx = (size_t)(b0 + row + r) * 16384 + ncol;   // real row of rn/out
            float v = fmaxf(acc[r] + b2f(rnb[ridx]), 0.f);
            if (last) out[ridx] = v;
            xs[(row + r) * 264 + nloc] = (short)f2b(v);
        }
    }
    // ---- phase 2 (wave-private x-stage: lgkmcnt orders RAW)
    f32x4 acc8[8] = {};
#pragma unroll
    for (int ks = 0; ks < 8; ++ks) {
        bf16x8 xf = *(const bf16x8*)(xs + l15 * 264 + ks * 32 + q8);
#pragma unroll
        for (int ot = 0; ot < 8; ++ot) {
            const unsigned short* bp = Abf + (size_t)(ot * 16 + l15) * 8192 + n0 + ks * 32 + q8;
            acc8[ot] = __builtin_amdgcn_mfma_f32_16x16x32_bf16(xf, *(const bf16x8*)bp, acc8[ot], 0, 0, 0);
        }
    }
    // ---- phase 3
    __syncthreads();
#pragma unroll
    for (int ot = 0; ot < 8; ++ot)
#pragma unroll
        for (int r = 0; r < 4; ++r)
            rs[(row + r) * 132 + ot * 16 + l15] = acc8[ot][r];
    __syncthreads();
#pragma unroll
    for (int e = t; e < 2048; e += 256) {
        int b = e >> 7, o = e & 127;
        float sAx = 0.f;
#pragma unroll
        for (int ww = 0; ww < 4; ++ww)
            sAx += ((const float*)(lds_buf + ww * 8448))[b * 132 + o];
        Axpart[(size_t)slab * 131072 + (size_t)(b0 + b) * 128 + o] = sAx;
    }
    // ---- zero imag rows of out (absorbed k_zero_imag)
    if (last) {
        float4 z4 = make_float4(0.f, 0.f, 0.f, 0.f);
        for (int e = t; e < 4096; e += 256) {
            int bb = e >> 8, nq = e & 255;
            *(float4*)(out + ((size_t)(b0 + bb) * 2 + 1) * N_ + slab * 1024 + nq * 4) = z4;
        }
    }
}

// ---------------------------------------------------------------------------
// per-step epilogue
__global__ __launch_bounds__(128) void k_small3(const float* Axpart, const float* uin,
                                                const float* y, const float* le,
                                                float* z, float* u, float* uout, int last) {
    __shared__ float red[2];
    int b = blockIdx.x, t = threadIdx.x;
    size_t idx = (size_t)b * 128 + t;
    float ax = 0.f;
#pragma unroll
    for (int s = 0; s < NS3; ++s) ax += Axpart[(size_t)s * 131072 + idx];
    float uo = uin[idx], yv = y[idx];
    float v = ax + uo - yv;
    float sq = v * v;
    for (int off = 32; off > 0; off >>= 1) sq += __shfl_down(sq, off, 64);
    if ((t & 63) == 0) red[t >> 6] = sq;
    __syncthreads();
    float tot = red[0] + red[1];
    float eps = expf(le[0]);
    float scale = fminf(1.f, eps / (sqrtf(tot) + 1e-12f));
    float zv = yv + v * scale;
    float un = uo + ax - zv;
    z[idx] = zv;
    u[idx] = un;
    if (last) uout[idx] = un;
}

// ---------------------------------------------------------------------------
extern "C" void kernel_launch(void* const* d_in, const int* in_sizes, int n_in,
                              void* d_out, int out_size, void* d_ws, size_t ws_size,
                              hipStream_t stream) {
    const float* rn  = (const float*)d_in[0];   // (B,2,N)
    const float* y   = (const float*)d_in[1];   // (B,2,M)
    const float* uin = (const float*)d_in[2];   // (B,2,M)
    const float* A   = (const float*)d_in[3];   // (2,M,N)
    const float* lr  = (const float*)d_in[4];   // log_rho
    const float* le  = (const float*)d_in[5];   // log_epsilon

    float* out = (float*)d_out;
    float* ws  = (float*)d_ws;

    float* Gpart  = ws;                             // 16*131072 = 2,097,152 f
    float* Axpart = Gpart + (size_t)NSG * 131072;   //  8*131072 = 1,048,576 f
    float* S      = Axpart + (size_t)NS3 * 131072;  // 8192
    float* AAHT   = S + 8192;                       // 8192
    float* Wt     = AAHT + 8192;                    // 8192
    float* z      = Wt + 8192;                      // 131072
    float* u      = z + 131072;                     // 131072
    unsigned short* qb  = (unsigned short*)(u + 131072);  // 131,072 us
    unsigned short* rnb = qb + 131072;              // B*2*N  = 16,777,216 us
    unsigned short* WgT = rnb + (size_t)B_ * 16384; // 128*16384 = 2,097,152 us
    unsigned short* Abf = WgT + 2097152;            // 2*64*8192 = 1,048,576 us
    unsigned short* ATb = Abf + 1048576;            // 8192*128  = 1,048,576 us
    float* uout = out + (size_t)B_ * 2 * N_;

    k_prep<<<128, 256, 0, stream>>>(A, Abf, WgT, ATb);
    k_cvt<<<8192, 256, 0, stream>>>(rn, rnb);
    k_Sbuild<<<2080, 256, 0, stream>>>(A, lr, S, AAHT);
    k_Ginv<<<1025, 256, 0, stream>>>(rnb, WgT, Gpart, S, Wt);

    for (int step = 0; step < 3; ++step) {
        const float* zp = (step == 0) ? y   : z;
        const float* up = (step == 0) ? uin : u;
        int last = (step == 2) ? 1 : 0;
        k_small12<<<256, 256, 0, stream>>>(Gpart, AAHT, Wt, zp, up, lr, qb);
        k_H23<<<dim3(NS3, 64), 256, 0, stream>>>(qb, ATb, rnb, Abf, out, Axpart, last);
        k_small3<<<B_, 128, 0, stream>>>(Axpart, up, y, le, z, u, uout, last);
    }
}

// Round 4
// 356.124 us; speedup vs baseline: 1.1815x; 1.0381x over previous
//
#include <hip/hip_runtime.h>

#define B_ 1024
#define M_ 64
#define N_ 8192
#define NSG 16   // k-splits for k_G  (chunk 1024 of K=16384)
#define NS3 8    // n-slabs for k_H23 (1024 cols each)

typedef __attribute__((ext_vector_type(8))) short bf16x8;
typedef __attribute__((ext_vector_type(4))) float f32x4;

__device__ inline unsigned short f2b(float f) {
    union { float f; unsigned u; } v; v.f = f;
    unsigned r = v.u + 0x7FFFu + ((v.u >> 16) & 1u);
    return (unsigned short)(r >> 16);
}
__device__ inline unsigned rne2(float lo, float hi) {
    union { float f; unsigned u; } a, b; a.f = lo; b.f = hi;
    unsigned x = (a.u + 0x7FFFu + ((a.u >> 16) & 1u)) >> 16;
    unsigned y = (b.u + 0x7FFFu + ((b.u >> 16) & 1u)) >> 16;
    return x | (y << 16);
}
__device__ inline float b2f(unsigned short s) {
    union { unsigned u; float f; } v; v.u = ((unsigned)s) << 16; return v.f;
}
// readlane with uniform (dynamic) lane index -> SALU broadcast (r8-proven)
__device__ inline float rl(float v, int l) {
    return __builtin_bit_cast(float, __builtin_amdgcn_readlane(__builtin_bit_cast(int, v), l));
}

// ---------------------------------------------------------------------------
// generic fp32 -> bf16 stream (8 elems/thread)
__global__ __launch_bounds__(256) void k_cvt(const float* src, unsigned short* dst) {
    size_t i = ((size_t)blockIdx.x * 256 + threadIdx.x) * 8;
    float4 f0 = *(const float4*)(src + i);
    float4 f1 = *(const float4*)(src + i + 4);
    union { bf16x8 v; unsigned u[4]; } r;
    r.u[0] = rne2(f0.x, f0.y); r.u[1] = rne2(f0.z, f0.w);
    r.u[2] = rne2(f1.x, f1.y); r.u[3] = rne2(f1.z, f1.w);
    *(bf16x8*)(dst + i) = r.v;
}

// ---------------------------------------------------------------------------
// Fused A-prep: one pass over A produces Abf (bf16 copy), ATb (transpose,
// [n][c*64+m]), WgT ([o][k]: o<64 -> [Ar|-Ai], o>=64 -> [Ai|Ar]).
__global__ __launch_bounds__(256) void k_prep(const float* A, unsigned short* Abf,
                                              unsigned short* WgT, unsigned short* ATb) {
    __shared__ float tile[128][65];
    int n0 = blockIdx.x * 64;
    int t = threadIdx.x;
    int nl = t % 64, r0 = t / 64;
#pragma unroll
    for (int it = 0; it < 32; ++it) {
        int row = r0 + it * 4;                       // row = c*64+m
        tile[row][nl] = A[(size_t)row * N_ + n0 + nl];
    }
    __syncthreads();
    // Abf + WgT (row-major reads of tile)
#pragma unroll
    for (int it = 0; it < 32; ++it) {
        int row = r0 + it * 4;
        float v = tile[row][nl];
        unsigned short bv = f2b(v);
        Abf[(size_t)row * N_ + n0 + nl] = bv;
        if (row < 64) {   // Ar[m]
            WgT[(size_t)row * 16384 + n0 + nl] = bv;                 // o=m,    k-low
            WgT[(size_t)(64 + row) * 16384 + 8192 + n0 + nl] = bv;   // o=64+m, k-high
        } else {          // Ai[m], m=row-64
            int m = row - 64;
            WgT[(size_t)m * 16384 + 8192 + n0 + nl] = f2b(-v);       // o=m,    k-high
            WgT[(size_t)(64 + m) * 16384 + n0 + nl] = bv;            // o=64+m, k-low
        }
    }
    // ATb (transposed reads)
    int o = t % 128, nn0 = t / 128;
#pragma unroll
    for (int it = 0; it < 32; ++it) {
        int nn = nn0 + it * 2;
        ATb[(size_t)(n0 + nn) * 128 + o] = f2b(tile[o][nn]);
    }
}

// ---------------------------------------------------------------------------
// S = I/(rho+1e-12) + A A^H  (complex 64x64, Hermitian). fp32.
__global__ __launch_bounds__(256) void k_Sbuild(const float* A, const float* lr,
                                                float* S, float* AAHT) {
    __shared__ float redS[8];
    int bid = blockIdx.x;
    int i = 0, rem = bid;
    while (rem >= 64 - i) { rem -= 64 - i; ++i; }
    int j = i + rem;                       // i <= j
    int t = threadIdx.x;
    const float* Ar = A;
    const float* Ai = A + (size_t)M_ * N_;
    const float* ari = Ar + (size_t)i * N_;
    const float* aii = Ai + (size_t)i * N_;
    const float* arj = Ar + (size_t)j * N_;
    const float* aij = Ai + (size_t)j * N_;
    float aR = 0.f, aI = 0.f;
#pragma unroll
    for (int it = 0; it < 8; ++it) {
        int n = it * 1024 + t * 4;
        float4 xr = *(const float4*)(ari + n);
        float4 xi = *(const float4*)(aii + n);
        float4 br = *(const float4*)(arj + n);
        float4 bi = *(const float4*)(aij + n);
        aR += xr.x * br.x + xi.x * bi.x + xr.y * br.y + xi.y * bi.y
            + xr.z * br.z + xi.z * bi.z + xr.w * br.w + xi.w * bi.w;
        aI += xi.x * br.x - xr.x * bi.x + xi.y * br.y - xr.y * bi.y
            + xi.z * br.z - xr.z * bi.z + xi.w * br.w - xr.w * bi.w;
    }
    for (int off = 32; off > 0; off >>= 1) {
        aR += __shfl_down(aR, off, 64);
        aI += __shfl_down(aI, off, 64);
    }
    int lane = t & 63, w = t >> 6;
    if (lane == 0) { redS[w * 2] = aR; redS[w * 2 + 1] = aI; }
    __syncthreads();
    if (t == 0) {
        float R = redS[0] + redS[2] + redS[4] + redS[6];
        float I = redS[1] + redS[3] + redS[5] + redS[7];
        float inv_rho = 1.0f / (expf(lr[0]) + 1e-12f);
        float diag = (i == j) ? inv_rho : 0.f;
        S[((size_t)i * 64 + j) * 2 + 0] = R + diag;
        S[((size_t)i * 64 + j) * 2 + 1] = I;
        AAHT[((size_t)j * 64 + i) * 2 + 0] = R;
        AAHT[((size_t)j * 64 + i) * 2 + 1] = I;
        if (i != j) {
            S[((size_t)j * 64 + i) * 2 + 0] = R;
            S[((size_t)j * 64 + i) * 2 + 1] = -I;
            AAHT[((size_t)i * 64 + j) * 2 + 0] = R;
            AAHT[((size_t)i * 64 + j) * 2 + 1] = -I;
        }
    }
}

// ---------------------------------------------------------------------------
// k_Ginv: heterogeneous fused kernel, grid = 1024.
//   block 0        : PANEL-4 blocked complex Gauss-Jordan inverse of S -> Wt,
//                    then falls through to its normal GEMM chunk (bx=0).
//                    Ownership: wave g owns cols c = 16q + 4g + j (q,j=0..3).
//                    Panel p (cols 4p..4p+3) owner = wave (p&3), local q=p>>2.
//                    Owner: 4 chained REGISTER-ONLY pivots on its 4 panel cols
//                    (pivot col is its own register state -> no LDS/barrier in
//                    the chain), publish Tp (4 cols, parity dbuf); ONE barrier;
//                    all waves rank-4 closed-form trail:
//                      col <- mask_panelrows(col) + Tp * s_orig   (r2-verified)
//                    Barriers 64 -> 16; chain ~31k cyc (~13us) vs r3's ~48us
//                    latency-bound 64-pivot loop. Register envelope ~55 live
//                    (r1-class), no panel-16 blowup (r2 lesson).
//                    Grid 1024 (not 1025): even if VGPR lands in (64,128] ->
//                    4 blocks/CU capacity = exactly 1024 slots, so ALL blocks
//                    are co-resident from t=0 (r2's straggler trap removed);
//                    block 0 just runs GJ then its chunk serially.
//   blocks 1..1023 : Gpart[split][b][o] = sum_k rnb[b][k] * WgT[o][k] (MFMA)
__global__ __launch_bounds__(256, 2) void k_Ginv(const unsigned short* rnb,
                                                 const unsigned short* WgT,
                                                 float* Gpart,
                                                 const float* S, float* Wt) {
    int t = threadIdx.x;
    int lane = t & 63;
    if (blockIdx.x == 0) {
        // ---------------- panel-4 blocked inversion ----------------
        __builtin_amdgcn_s_setprio(1);
        __shared__ float2 Tp[2][4][64];   // [parity][panel col j][row]
        int g = t >> 6;
        float mx0,my0,mx1,my1,mx2,my2,mx3,my3,mx4,my4,mx5,my5,mx6,my6,mx7,my7;
        float mx8,my8,mx9,my9,mx10,my10,mx11,my11,mx12,my12,mx13,my13,mx14,my14,mx15,my15;
        // col mapping: J=4q+j -> c = 16q + 4g + j
#define GJ_INIT(J) { int c = 16 * ((J) >> 2) + 4 * g + ((J) & 3);            \
    float2 v = ((const float2*)S)[(size_t)lane * 64 + c];                    \
    mx##J = v.x; my##J = v.y; }
        GJ_INIT(0) GJ_INIT(1) GJ_INIT(2) GJ_INIT(3) GJ_INIT(4) GJ_INIT(5) GJ_INIT(6) GJ_INIT(7)
        GJ_INIT(8) GJ_INIT(9) GJ_INIT(10) GJ_INIT(11) GJ_INIT(12) GJ_INIT(13) GJ_INIT(14) GJ_INIT(15)
#undef GJ_INIT

// one in-register pivot on own panel: pivot col JA (k=4p+jj), update JB0..2 + JA
#define PIV(JA, JB0, JB1, JB2, jj) {                                         \
    int k = p4 + (jj);                                                       \
    float px = rl(mx##JA, k), py = rl(my##JA, k);                            \
    float d = px * px + py * py;                                             \
    float id = 1.0f / d;                                                     \
    float pix = px * id, piy = -py * id;                                     \
    bool isk = (lane == k);                                                  \
    float a   = isk ? 0.f : 1.f;                                             \
    float fpx = isk ? -pix : (mx##JA * pix - my##JA * piy);                  \
    float fpy = isk ? -piy : (mx##JA * piy + my##JA * pix);                  \
    { float sx = rl(mx##JB0, k), sy = rl(my##JB0, k);                        \
      float nx = a * mx##JB0 - (fpx * sx - fpy * sy);                        \
      float ny = a * my##JB0 - (fpx * sy + fpy * sx);                        \
      mx##JB0 = nx; my##JB0 = ny; }                                          \
    { float sx = rl(mx##JB1, k), sy = rl(my##JB1, k);                        \
      float nx = a * mx##JB1 - (fpx * sx - fpy * sy);                        \
      float ny = a * my##JB1 - (fpx * sy + fpy * sx);                        \
      mx##JB1 = nx; my##JB1 = ny; }                                          \
    { float sx = rl(mx##JB2, k), sy = rl(my##JB2, k);                        \
      float nx = a * mx##JB2 - (fpx * sx - fpy * sy);                        \
      float ny = a * my##JB2 - (fpx * sy + fpy * sx);                        \
      mx##JB2 = nx; my##JB2 = ny; }                                          \
    mx##JA = -fpx; my##JA = -fpy; }

#define FACT4(J0, J1, J2, J3) {                                              \
    PIV(J0, J1, J2, J3, 0) PIV(J1, J0, J2, J3, 1)                            \
    PIV(J2, J0, J1, J3, 2) PIV(J3, J0, J1, J2, 3)                            \
    Tp[buf][0][lane] = make_float2(mx##J0, my##J0);                          \
    Tp[buf][1][lane] = make_float2(mx##J1, my##J1);                          \
    Tp[buf][2][lane] = make_float2(mx##J2, my##J2);                          \
    Tp[buf][3][lane] = make_float2(mx##J3, my##J3); }

        for (int p = 0; p < 16; ++p) {
            const int buf = p & 1;
            const int p4  = p * 4;
            const int q   = p >> 2;
            const bool own = (g == (p & 3));
            if (own) {
                switch (q) {
                    case 0:  FACT4(0, 1, 2, 3)     break;
                    case 1:  FACT4(4, 5, 6, 7)     break;
                    case 2:  FACT4(8, 9, 10, 11)   break;
                    default: FACT4(12, 13, 14, 15) break;
                }
            }
            __syncthreads();
            float2 t0 = Tp[buf][0][lane];
            float2 t1 = Tp[buf][1][lane];
            float2 t2 = Tp[buf][2][lane];
            float2 t3 = Tp[buf][3][lane];
            float msk = ((lane >> 2) == p) ? 0.f : 1.f;
            int skipq = own ? q : -1;
// closed-form rank-4 update: col <- msk*col + Tp * s_orig (s read before write)
#define TRAIL(J) if (((J) >> 2) != skipq) {                                  \
    float s0x = rl(mx##J, p4),     s0y = rl(my##J, p4);                      \
    float s1x = rl(mx##J, p4 + 1), s1y = rl(my##J, p4 + 1);                  \
    float s2x = rl(mx##J, p4 + 2), s2y = rl(my##J, p4 + 2);                  \
    float s3x = rl(mx##J, p4 + 3), s3y = rl(my##J, p4 + 3);                  \
    float ax = msk * mx##J, ay = msk * my##J;                                \
    ax += t0.x * s0x - t0.y * s0y; ay += t0.x * s0y + t0.y * s0x;            \
    ax += t1.x * s1x - t1.y * s1y; ay += t1.x * s1y + t1.y * s1x;            \
    ax += t2.x * s2x - t2.y * s2y; ay += t2.x * s2y + t2.y * s2x;            \
    ax += t3.x * s3x - t3.y * s3y; ay += t3.x * s3y + t3.y * s3x;            \
    mx##J = ax; my##J = ay; }
            TRAIL(0)  TRAIL(1)  TRAIL(2)  TRAIL(3)
            TRAIL(4)  TRAIL(5)  TRAIL(6)  TRAIL(7)
            TRAIL(8)  TRAIL(9)  TRAIL(10) TRAIL(11)
            TRAIL(12) TRAIL(13) TRAIL(14) TRAIL(15)
#undef TRAIL
        }
#undef FACT4
#undef PIV
#define GJ_OUT(J) { int c = 16 * ((J) >> 2) + 4 * g + ((J) & 3);             \
    ((float2*)Wt)[(size_t)c * 64 + lane] = make_float2(mx##J, my##J); }
        GJ_OUT(0) GJ_OUT(1) GJ_OUT(2) GJ_OUT(3) GJ_OUT(4) GJ_OUT(5) GJ_OUT(6) GJ_OUT(7)
        GJ_OUT(8) GJ_OUT(9) GJ_OUT(10) GJ_OUT(11) GJ_OUT(12) GJ_OUT(13) GJ_OUT(14) GJ_OUT(15)
#undef GJ_OUT
        __builtin_amdgcn_s_setprio(0);
        // fall through: block 0 also runs its GEMM chunk (bx = 0)
    }
    // ---------------- GEMM path (k_G) ----------------
    int bx = blockIdx.x;
    int w = t >> 6;
    int l15 = lane & 15;
    int q8 = (lane >> 4) * 8;
    int split = bx & 15;
    int b0 = (bx >> 4) * 16;
    int k0 = split * 1024;
    f32x4 a00 = {}, a01 = {};
    const unsigned short* x0 = rnb + (size_t)(b0 + l15) * 16384 + k0 + q8;
    const unsigned short* w0 = WgT + (size_t)(w * 32 + l15) * 16384 + k0 + q8;
    const unsigned short* w1 = w0 + (size_t)16 * 16384;
#pragma unroll 8
    for (int ks = 0; ks < 32; ++ks) {
        int kk = ks * 32;
        bf16x8 af0 = *(const bf16x8*)(x0 + kk);
        bf16x8 bf0 = *(const bf16x8*)(w0 + kk);
        bf16x8 bf1 = *(const bf16x8*)(w1 + kk);
        a00 = __builtin_amdgcn_mfma_f32_16x16x32_bf16(af0, bf0, a00, 0, 0, 0);
        a01 = __builtin_amdgcn_mfma_f32_16x16x32_bf16(af0, bf1, a01, 0, 0, 0);
    }
    int row = (lane >> 4) * 4;
    size_t base = (size_t)split * (B_ * 128);
    float* g = Gpart + base + (size_t)(b0 + row) * 128 + w * 32 + l15;
#pragma unroll
    for (int r = 0; r < 4; ++r) {
        g[(size_t)r * 128] = a00[r];
        g[(size_t)r * 128 + 16] = a01[r];
    }
}

// ---------------------------------------------------------------------------
// per-step small: Ab = sum(Gpart) + rho*AAH*(z-u);  qb = bf16(rho*(z-u) - S^-1*Ab)
__global__ __launch_bounds__(256) void k_small12(const float* Gpart, const float* AAHT,
                                                 const float* Wt, const float* zin,
                                                 const float* uin, const float* lr,
                                                 unsigned short* qb) {
    __shared__ float2 AbS[4][64];
    int t = threadIdx.x;
    int m = t & 63;
    int w = __builtin_amdgcn_readfirstlane(t >> 6);
    int b = blockIdx.x * 4 + w;
    float rho = expf(lr[0]);
    float abR = 0.f, abI = 0.f;
    for (int k = 0; k < 64; ++k) {
        float wr = zin[(b * 2 + 0) * 64 + k] - uin[(b * 2 + 0) * 64 + k];
        float wi = zin[(b * 2 + 1) * 64 + k] - uin[(b * 2 + 1) * 64 + k];
        float2 h = *(const float2*)(AAHT + ((size_t)k * 64 + m) * 2);  // AAH[m][k]
        abR += wr * h.x - wi * h.y;
        abI += wi * h.x + wr * h.y;
    }
    float gR = 0.f, gI = 0.f;
#pragma unroll
    for (int s = 0; s < NSG; ++s) {
        gR += Gpart[(size_t)s * 131072 + (size_t)b * 128 + m];
        gI += Gpart[(size_t)s * 131072 + (size_t)b * 128 + 64 + m];
    }
    abR = gR + rho * abR;
    abI = gI + rho * abI;
    AbS[w][m] = make_float2(abR, abI);
    __syncthreads();
    float tR = 0.f, tI = 0.f;
    for (int k = 0; k < 64; ++k) {
        float2 Wv = *(const float2*)(Wt + ((size_t)k * 64 + m) * 2);   // W[m][k]
        float2 ab = AbS[w][k];
        tR += ab.x * Wv.x - ab.y * Wv.y;
        tI += ab.y * Wv.x + ab.x * Wv.y;
    }
    float wr_m = zin[(b * 2 + 0) * 64 + m] - uin[(b * 2 + 0) * 64 + m];
    float wi_m = zin[(b * 2 + 1) * 64 + m] - uin[(b * 2 + 1) * 64 + m];
    qb[(size_t)b * 128 + m] = f2b(rho * wr_m - tR);
    qb[(size_t)b * 128 + 64 + m] = f2b(rho * wi_m - tI);
}

// ---------------------------------------------------------------------------
// k_H23: fused x-update + Ax partials; last step also writes fp32 out (real)
// and zeros the imag rows (absorbs k_zero_imag). rn read as bf16 (rnb).
__global__ __launch_bounds__(256, 3) void k_H23(const unsigned short* qb, const unsigned short* ATb,
                                                const unsigned short* rnb, const unsigned short* Abf,
                                                float* out, float* Axpart, int last) {
    __shared__ __align__(16) char lds_buf[4 * 8448];
    int t = threadIdx.x;
    int lane = t & 63;
    int w = t >> 6;
    int l15 = lane & 15;
    int q8 = (lane >> 4) * 8;
    int row = (lane >> 4) * 4;
    int slab = blockIdx.x;
    int b0 = blockIdx.y * 16;
    int n0 = slab * 1024 + w * 256;
    short* xs = (short*)(lds_buf + w * 8448);      // [16][264] bf16 (row stride 528B)
    float* rs = (float*)(lds_buf + w * 8448);      // [16][132] fp32 alias (same wave only)

    // ---- phase 1
    bf16x8 a[4];
    const unsigned short* qrow = qb + (size_t)(b0 + l15) * 128 + q8;
#pragma unroll
    for (int ks = 0; ks < 4; ++ks) a[ks] = *(const bf16x8*)(qrow + ks * 32);
#pragma unroll 2
    for (int nt = 0; nt < 16; ++nt) {
        f32x4 acc = {};
        const unsigned short* bbase = ATb + (size_t)(n0 + nt * 16 + l15) * 128 + q8;
#pragma unroll
        for (int ks = 0; ks < 4; ++ks) {
            bf16x8 bf = *(const bf16x8*)(bbase + ks * 32);
            acc = __builtin_amdgcn_mfma_f32_16x16x32_bf16(a[ks], bf, acc, 0, 0, 0);
        }
        int ncol = n0 + nt * 16 + l15;
        int nloc = nt * 16 + l15;
#pragma unroll
        for (int r = 0; r < 4; ++r) {
            size_t ridx = (size_t)(b0 + row + r) * 16384 + ncol;   // real row of rn/out
            float v = fmaxf(acc[r] + b2f(rnb[ridx]), 0.f);
            if (last) out[ridx] = v;
            xs[(row + r) * 264 + nloc] = (short)f2b(v);
        }
    }
    // ---- phase 2 (wave-private x-stage: lgkmcnt orders RAW)
    f32x4 acc8[8] = {};
#pragma unroll
    for (int ks = 0; ks < 8; ++ks) {
        bf16x8 xf = *(const bf16x8*)(xs + l15 * 264 + ks * 32 + q8);
#pragma unroll
        for (int ot = 0; ot < 8; ++ot) {
            const unsigned short* bp = Abf + (size_t)(ot * 16 + l15) * 8192 + n0 + ks * 32 + q8;
            acc8[ot] = __builtin_amdgcn_mfma_f32_16x16x32_bf16(xf, *(const bf16x8*)bp, acc8[ot], 0, 0, 0);
        }
    }
    // ---- phase 3
    __syncthreads();
#pragma unroll
    for (int ot = 0; ot < 8; ++ot)
#pragma unroll
        for (int r = 0; r < 4; ++r)
            rs[(row + r) * 132 + ot * 16 + l15] = acc8[ot][r];
    __syncthreads();
#pragma unroll
    for (int e = t; e < 2048; e += 256) {
        int b = e >> 7, o = e & 127;
        float sAx = 0.f;
#pragma unroll
        for (int ww = 0; ww < 4; ++ww)
            sAx += ((const float*)(lds_buf + ww * 8448))[b * 132 + o];
        Axpart[(size_t)slab * 131072 + (size_t)(b0 + b) * 128 + o] = sAx;
    }
    // ---- zero imag rows of out (absorbed k_zero_imag)
    if (last) {
        float4 z4 = make_float4(0.f, 0.f, 0.f, 0.f);
        for (int e = t; e < 4096; e += 256) {
            int bb = e >> 8, nq = e & 255;
            *(float4*)(out + ((size_t)(b0 + bb) * 2 + 1) * N_ + slab * 1024 + nq * 4) = z4;
        }
    }
}

// ---------------------------------------------------------------------------
// per-step epilogue
__global__ __launch_bounds__(128) void k_small3(const float* Axpart, const float* uin,
                                                const float* y, const float* le,
                                                float* z, float* u, float* uout, int last) {
    __shared__ float red[2];
    int b = blockIdx.x, t = threadIdx.x;
    size_t idx = (size_t)b * 128 + t;
    float ax = 0.f;
#pragma unroll
    for (int s = 0; s < NS3; ++s) ax += Axpart[(size_t)s * 131072 + idx];
    float uo = uin[idx], yv = y[idx];
    float v = ax + uo - yv;
    float sq = v * v;
    for (int off = 32; off > 0; off >>= 1) sq += __shfl_down(sq, off, 64);
    if ((t & 63) == 0) red[t >> 6] = sq;
    __syncthreads();
    float tot = red[0] + red[1];
    float eps = expf(le[0]);
    float scale = fminf(1.f, eps / (sqrtf(tot) + 1e-12f));
    float zv = yv + v * scale;
    float un = uo + ax - zv;
    z[idx] = zv;
    u[idx] = un;
    if (last) uout[idx] = un;
}

// ---------------------------------------------------------------------------
extern "C" void kernel_launch(void* const* d_in, const int* in_sizes, int n_in,
                              void* d_out, int out_size, void* d_ws, size_t ws_size,
                              hipStream_t stream) {
    const float* rn  = (const float*)d_in[0];   // (B,2,N)
    const float* y   = (const float*)d_in[1];   // (B,2,M)
    const float* uin = (const float*)d_in[2];   // (B,2,M)
    const float* A   = (const float*)d_in[3];   // (2,M,N)
    const float* lr  = (const float*)d_in[4];   // log_rho
    const float* le  = (const float*)d_in[5];   // log_epsilon

    float* out = (float*)d_out;
    float* ws  = (float*)d_ws;

    float* Gpart  = ws;                             // 16*131072 = 2,097,152 f
    float* Axpart = Gpart + (size_t)NSG * 131072;   //  8*131072 = 1,048,576 f
    float* S      = Axpart + (size_t)NS3 * 131072;  // 8192
    float* AAHT   = S + 8192;                       // 8192
    float* Wt     = AAHT + 8192;                    // 8192
    float* z      = Wt + 8192;                      // 131072
    float* u      = z + 131072;                     // 131072
    unsigned short* qb  = (unsigned short*)(u + 131072);  // 131,072 us
    unsigned short* rnb = qb + 131072;              // B*2*N  = 16,777,216 us
    unsigned short* WgT = rnb + (size_t)B_ * 16384; // 128*16384 = 2,097,152 us
    unsigned short* Abf = WgT + 2097152;            // 2*64*8192 = 1,048,576 us
    unsigned short* ATb = Abf + 1048576;            // 8192*128  = 1,048,576 us
    float* uout = out + (size_t)B_ * 2 * N_;

    k_prep<<<128, 256, 0, stream>>>(A, Abf, WgT, ATb);
    k_cvt<<<8192, 256, 0, stream>>>(rn, rnb);
    k_Sbuild<<<2080, 256, 0, stream>>>(A, lr, S, AAHT);
    k_Ginv<<<1024, 256, 0, stream>>>(rnb, WgT, Gpart, S, Wt);

    for (int step = 0; step < 3; ++step) {
        const float* zp = (step == 0) ? y   : z;
        const float* up = (step == 0) ? uin : u;
        int last = (step == 2) ? 1 : 0;
        k_small12<<<256, 256, 0, stream>>>(Gpart, AAHT, Wt, zp, up, lr, qb);
        k_H23<<<dim3(NS3, 64), 256, 0, stream>>>(qb, ATb, rnb, Abf, out, Axpart, last);
        k_small3<<<B_, 128, 0, stream>>>(Axpart, up, y, le, z, u, uout, last);
    }
}